// Round 17
// baseline (534.801 us; speedup 1.0000x reference)
//
#include <hip/hip_runtime.h>

// Problem constants (fixed by the reference)
constexpr int Bc = 32, Sc = 1024, Hc = 256, Pc = 96, Lc = 200, Oc = 200, Ec = 64;
constexpr int Mtot = Bc * Sc;
constexpr float DT = 0.25f;     // 1/N_EULER
constexpr int KP = 224;         // padded L/O dim (7*32)

enum { MODE_ENC = 0, MODE_QKV = 3, MODE_OUT = 4, MODE_BF16OUT = 5 };

typedef short bf16x8 __attribute__((ext_vector_type(8)));
typedef float f32x4 __attribute__((ext_vector_type(4)));
typedef unsigned short u16x8 __attribute__((ext_vector_type(8)));

__device__ inline unsigned short f2bf(float x) {
    union { float f; unsigned int u; } v; v.f = x;
    unsigned int r = v.u + 0x7FFFu + ((v.u >> 16) & 1u);   // RNE
    return (unsigned short)(r >> 16);
}
__device__ inline float bf2f(unsigned short x) {
    union { unsigned int u; float f; } v; v.u = ((unsigned int)x) << 16;
    return v.f;
}
__device__ inline float fast_tanh(float x) {
    float cx = fminf(fmaxf(x, -15.f), 15.f);
    float e = __expf(2.f * cx);
    return __fdividef(e - 1.f, e + 1.f);
}

// ---------------------------------------------------------------------------
__global__ __launch_bounds__(256) void eco_kernel(
    const float* __restrict__ eco_data, const float* __restrict__ W_eco,
    const float* __restrict__ b_eco, float* __restrict__ eco_vec)
{
    const int b = blockIdx.x, h = threadIdx.x;
    float acc = b_eco[h];
    #pragma unroll
    for (int e = 0; e < Ec; e++)
        acc = fmaf(eco_data[b * Ec + e], W_eco[(size_t)e * Hc + h], acc);
    eco_vec[(size_t)b * Hc + h] = acc;
}

// ---------------------------------------------------------------------------
// W fp32 [K][N] (z slices) -> WT bf16 [Npad][Kpad], zero-padded.
// ---------------------------------------------------------------------------
__global__ void wtrans_kernel(const float* __restrict__ W, unsigned short* __restrict__ WT,
                              int K, int N, int Kpad, int Npad)
{
    const int z = blockIdx.z;
    const int n = blockIdx.x * 16 + threadIdx.x;
    const int k = blockIdx.y * 16 + threadIdx.y;
    if (n >= Npad || k >= Kpad) return;
    float v = (n < N && k < K) ? W[(size_t)z * K * N + (size_t)k * N + n] : 0.f;
    WT[(size_t)z * Npad * Kpad + (size_t)n * Kpad + k] = f2bf(v);
}

// ---------------------------------------------------------------------------
// bf16 MFMA GEMM, 128x128 tile, 4 waves of 64x64, 16x16x32 MFMA.
// MODE_QKV z==2 writes V^T via an LDS bounce (two 64-row halves) instead of
// the 2KB-strided scalar u16 scatter (8x write amplification) — r14: -27 us.
// ---------------------------------------------------------------------------
template <int MODE, typename TA>
__global__ __launch_bounds__(256) void mfma_gemm(
    const TA* __restrict__ A, const unsigned short* __restrict__ WT,
    const float* __restrict__ bias, void* __restrict__ Cv,
    int M, int N, int K, int Kpad,
    size_t aStrideZ, size_t wStrideZ, size_t bStrideZ, size_t cStrideZ,
    const float* __restrict__ timev, const float* __restrict__ wtv,
    const float* __restrict__ eco, const float* __restrict__ trandat,
    unsigned short* __restrict__ Ck, unsigned short* __restrict__ Cvt)
{
    constexpr int LDS_S = 40;
    __shared__ unsigned short SM[128 * LDS_S * 2];   // As | Bs
    unsigned short* As = SM;
    unsigned short* Bs = SM + 128 * LDS_S;

    const int tid = threadIdx.x;
    const int z = blockIdx.z;
    const int m0 = blockIdx.y * 128;
    const int n0 = blockIdx.x * 128;

    A    += (size_t)z * aStrideZ;
    WT   += (size_t)z * wStrideZ;
    bias += (size_t)z * bStrideZ;
    float* Cf = (float*)Cv + (size_t)z * cStrideZ;
    unsigned short* Cu = (unsigned short*)Cv + (size_t)z * cStrideZ;
    const float* wtp = wtv ? (wtv + (size_t)z * Lc) : nullptr;

    const int lane = tid & 63, wave = tid >> 6;
    const int wm = (wave & 1) * 64, wn = (wave >> 1) * 64;
    const int fm = lane & 15, fq = lane >> 4;

    f32x4 acc[4][4];
    #pragma unroll
    for (int i = 0; i < 4; i++)
        #pragma unroll
        for (int j = 0; j < 4; j++)
            acc[i][j] = (f32x4){0.f, 0.f, 0.f, 0.f};

    for (int k0 = 0; k0 < K; k0 += 32) {
        if (k0) __syncthreads();
        #pragma unroll
        for (int i = 0; i < 4; i++) {
            const int f = i * 256 + tid;
            const int row = f >> 3, kq = f & 7;
            const int k = k0 + kq * 4;
            ushort4 s;
            if constexpr (sizeof(TA) == 4) {
                float4 v = {0.f, 0.f, 0.f, 0.f};
                if (k < K) v = *(const float4*)((const float*)A + (size_t)(m0 + row) * K + k);
                s.x = f2bf(v.x); s.y = f2bf(v.y); s.z = f2bf(v.z); s.w = f2bf(v.w);
            } else {
                s = make_ushort4(0, 0, 0, 0);
                if (k < K) s = *(const ushort4*)((const unsigned short*)A + (size_t)(m0 + row) * K + k);
            }
            *(ushort4*)&As[row * LDS_S + kq * 4] = s;
        }
        #pragma unroll
        for (int i = 0; i < 2; i++) {
            const int f = i * 256 + tid;
            const int row = f >> 2, q = f & 3;
            u16x8 v = *(const u16x8*)(WT + (size_t)(n0 + row) * Kpad + k0 + q * 8);
            *(u16x8*)&Bs[row * LDS_S + q * 8] = v;
        }
        __syncthreads();

        bf16x8 af[4], bfr[4];
        #pragma unroll
        for (int mi = 0; mi < 4; mi++)
            af[mi] = *(const bf16x8*)&As[(wm + mi * 16 + fm) * LDS_S + fq * 8];
        #pragma unroll
        for (int nj = 0; nj < 4; nj++)
            bfr[nj] = *(const bf16x8*)&Bs[(wn + nj * 16 + fm) * LDS_S + fq * 8];
        #pragma unroll
        for (int mi = 0; mi < 4; mi++)
            #pragma unroll
            for (int nj = 0; nj < 4; nj++)
                acc[mi][nj] = __builtin_amdgcn_mfma_f32_16x16x32_bf16(
                    af[mi], bfr[nj], acc[mi][nj], 0, 0, 0);
    }

    // ---- V^T epilogue (MODE_QKV, z==2): LDS bounce, coalesced writes ----
    if (MODE == MODE_QKV && z == 2) {
        constexpr int BSTR = 136;   // bounce row stride (u16)
        const int bq = m0 >> 10, sq0 = m0 & (Sc - 1);
        const int myhalf = wn >> 6;             // wave's n-half (0 or 1)
        #pragma unroll
        for (int half = 0; half < 2; half++) {
            __syncthreads();                    // SM free
            if (myhalf == half) {
                #pragma unroll
                for (int mi = 0; mi < 4; mi++)
                    #pragma unroll
                    for (int nj = 0; nj < 4; nj++) {
                        const int nn = n0 + wn + nj * 16 + fm;
                        const float bv = bias[nn];
                        const float ev = eco[(size_t)bq * Hc + nn];
                        #pragma unroll
                        for (int r = 0; r < 4; r++) {
                            const int mm = m0 + wm + mi * 16 + fq * 4 + r;
                            float v = acc[mi][nj][r] + bv + ev;
                            if (trandat[(size_t)mm * Hc + (Hc - 1)] == 0.f) v = 0.f;
                            SM[(nj * 16 + fm) * BSTR + wm + mi * 16 + fq * 4 + r] = f2bf(v);
                        }
                    }
            }
            __syncthreads();                    // bounce half ready
            #pragma unroll
            for (int i = 0; i < 4; i++) {
                const int vv = i * 256 + tid;   // 1024 = 64 rows x 16 vecs
                const int nl = vv >> 4, vc = vv & 15;
                *(u16x8*)&Cvt[((size_t)bq * Hc + n0 + half * 64 + nl) * Sc + sq0 + vc * 8] =
                    *(const u16x8*)&SM[nl * BSTR + vc * 8];
            }
        }
        return;
    }

    // ---- standard epilogue: C/D layout col = lane&15, row = quad*4 + reg ----
    #pragma unroll
    for (int mi = 0; mi < 4; mi++) {
        #pragma unroll
        for (int nj = 0; nj < 4; nj++) {
            const int nn = n0 + wn + nj * 16 + fm;
            if (nn >= N) continue;
            const float bv = (MODE == MODE_BF16OUT) ? 0.f
                           : ((MODE == MODE_ENC && nn >= Lc) ? 0.f : bias[nn]);
            #pragma unroll
            for (int r = 0; r < 4; r++) {
                const int mm = m0 + wm + mi * 16 + fq * 4 + r;
                float v = acc[mi][nj][r] + bv;
                if (MODE == MODE_ENC) {
                    float vv = (nn < Lc) ? fast_tanh(v + timev[mm] * wtp[nn]) : 0.f;
                    Cu[(size_t)mm * N + nn] = f2bf(vv);
                } else if (MODE == MODE_QKV) {
                    v += eco[(size_t)(mm >> 10) * Hc + nn];
                    if (trandat[(size_t)mm * Hc + (Hc - 1)] == 0.f) v = 0.f;
                    if (z == 0)      ((unsigned short*)Cv)[(size_t)mm * Hc + nn] = f2bf(v * 0.0625f);
                    else             Ck[(size_t)mm * Hc + nn] = f2bf(v);
                } else if (MODE == MODE_BF16OUT) {
                    Cu[(size_t)mm * N + nn] = f2bf(v);
                } else {
                    Cf[(size_t)mm * N + nn] = v;
                }
            }
        }
    }
}

// ---------------------------------------------------------------------------
// Fused 4-iteration Euler solve — r5's structure (fastest: 216.6 us) with
// ONE change: per-thread bias caches (14 arch VGPRs) moved to LDS.
// Register audit at the 512-thread 128-total-reg cap: hidp 28 + pr 8 +
// addr ~30 = ~66 arch + 56 acc = ~122 <= 128 (r5 was ~136 -> 8-reg spill,
// 38 MB scratch stores = WRITE 81 vs 43 MB ideal). Everything else verbatim:
// dbuf W + dbuf hid-chunk LDS, 1 barrier/chunk, h update = LDS RMW.
// Dynamic LDS 117,504 B.
// ---------------------------------------------------------------------------
__global__ __launch_bounds__(512, 2) void euler_fused(
    unsigned short* __restrict__ hg,       // [3][M][224] bf16, in/out
    const unsigned short* __restrict__ W1, // [3][256][224] bf16
    const unsigned short* __restrict__ W2, // [3][256][224] bf16
    const float* __restrict__ b1g, const float* __restrict__ b2g)
{
    constexpr int HS = 232;   // h LDS stride (u16)
    constexpr int WS = 40;    // W / hid chunk stride (u16)
    extern __shared__ unsigned short lds[];
    unsigned short* hs  = lds;                 // [128][232]  59,392 B
    unsigned short* wsb[2] = { lds + 29696, lds + 38656 };   // [224][40] each
    unsigned short* hcb[2] = { lds + 47616, lds + 52736 };   // [128][40] each
    float* bfl = (float*)(lds + 57856);        // b1[224] | b2[224]  1,792 B

    const int tid = threadIdx.x;
    const int z = blockIdx.y;
    const int m0 = blockIdx.x * 128;
    unsigned short* hrow = hg + ((size_t)z * Mtot + m0) * KP;
    const unsigned short* W1z = W1 + (size_t)z * 256 * KP;
    const unsigned short* W2z = W2 + (size_t)z * 256 * KP;

    const int lane = tid & 63, w = tid >> 6;
    const int wm = (w & 3) * 32, wn = (w >> 2) * 112;
    const int fm = lane & 15, fq = lane >> 4;

    // staging geometry: 224 rows x 4 u16x8 per chunk = 896 vec-elems / 512 thr
    const int sr = tid >> 2, sq = tid & 3;
    const bool s2 = (tid < 384);

    // biases -> LDS (first read after phase-1 k-loop, many barriers later)
    if (tid < 448) {
        const int n = (tid < 224) ? tid : tid - 224;
        float v = 0.f;
        if (tid < 224) { if (n < Oc) v = b1g[z * Oc + n]; }
        else           { if (n < Lc) v = b2g[z * Lc + n]; }
        bfl[tid] = v;
    }

    // prefetch W1 chunk 0
    u16x8 pr0, pr1;
    pr0 = *(const u16x8*)&W1z[sr * KP + sq * 8];
    if (s2) pr1 = *(const u16x8*)&W1z[(sr + 128) * KP + sq * 8];

    // stage h tile: 128 x 224
    #pragma unroll
    for (int i = 0; i < 7; i++) {
        const int f = i * 512 + tid;
        const int r = f / 28, c = (f % 28) * 8;
        *(u16x8*)&hs[r * HS + c] = *(const u16x8*)&hrow[(size_t)r * KP + c];
    }

    for (int it = 0; it < 4; it++) {
        // ================= phase 1: hid = tanh(h @ W1 + b1) =================
        __syncthreads();                       // B0: hs/update visible, ws free
        *(u16x8*)&wsb[0][sr * WS + sq * 8] = pr0;
        if (s2) *(u16x8*)&wsb[0][(sr + 128) * WS + sq * 8] = pr1;
        pr0 = *(const u16x8*)&W1z[sr * KP + 32 + sq * 8];
        if (s2) pr1 = *(const u16x8*)&W1z[(sr + 128) * KP + 32 + sq * 8];
        __syncthreads();                       // B1: ws[0] ready

        f32x4 acc[2][7];
        #pragma unroll
        for (int mi = 0; mi < 2; mi++)
            #pragma unroll
            for (int nj = 0; nj < 7; nj++)
                acc[mi][nj] = (f32x4){0.f, 0.f, 0.f, 0.f};

        for (int k = 0; k < 7; k++) {
            if (k < 6) {
                unsigned short* wb = wsb[(k + 1) & 1];
                *(u16x8*)&wb[sr * WS + sq * 8] = pr0;
                if (s2) *(u16x8*)&wb[(sr + 128) * WS + sq * 8] = pr1;
                const unsigned short* src = (k + 2 < 7) ? (W1z + (k + 2) * 32) : W2z;
                pr0 = *(const u16x8*)&src[sr * KP + sq * 8];
                if (s2) pr1 = *(const u16x8*)&src[(sr + 128) * KP + sq * 8];
            }
            const unsigned short* wr = wsb[k & 1];
            bf16x8 af[2], bfr[7];
            #pragma unroll
            for (int mi = 0; mi < 2; mi++)
                af[mi] = *(const bf16x8*)&hs[(wm + mi * 16 + fm) * HS + k * 32 + fq * 8];
            #pragma unroll
            for (int nj = 0; nj < 7; nj++)
                bfr[nj] = *(const bf16x8*)&wr[(wn + nj * 16 + fm) * WS + fq * 8];
            #pragma unroll
            for (int mi = 0; mi < 2; mi++)
                #pragma unroll
                for (int nj = 0; nj < 7; nj++)
                    acc[mi][nj] = __builtin_amdgcn_mfma_f32_16x16x32_bf16(
                        af[mi], bfr[nj], acc[mi][nj], 0, 0, 0);
            __syncthreads();
        }

        // bias + tanh, pack (C layout: col = fm, row = fq*4+r)
        unsigned short hidp[2][7][4];
        #pragma unroll
        for (int mi = 0; mi < 2; mi++)
            #pragma unroll
            for (int nj = 0; nj < 7; nj++) {
                const float b1v = bfl[wn + nj * 16 + fm];
                #pragma unroll
                for (int r = 0; r < 4; r++)
                    hidp[mi][nj][r] = f2bf(fast_tanh(acc[mi][nj][r] + b1v));
            }

        // ================= phase 2: h += DT * (hid @ W2 + b2) ===============
        {
            *(u16x8*)&wsb[0][sr * WS + sq * 8] = pr0;
            if (s2) *(u16x8*)&wsb[0][(sr + 128) * WS + sq * 8] = pr1;
            pr0 = *(const u16x8*)&W2z[sr * KP + 32 + sq * 8];
            if (s2) pr1 = *(const u16x8*)&W2z[(sr + 128) * KP + 32 + sq * 8];
            // hid chunk 0 -> hc[0]
            #pragma unroll
            for (int t2 = 0; t2 < 2; t2++) {
                const int c0 = t2 * 16;
                if (c0 >= wn && c0 < wn + 112) {
                    const int nj = (c0 - wn) >> 4;
                    #pragma unroll
                    for (int mi = 0; mi < 2; mi++)
                        #pragma unroll
                        for (int r = 0; r < 4; r++)
                            hcb[0][(wm + mi * 16 + fq * 4 + r) * WS + t2 * 16 + fm] =
                                hidp[mi][nj][r];
                }
            }
        }
        __syncthreads();                       // ws[0]/hc[0] ready

        f32x4 fac[2][7];
        #pragma unroll
        for (int mi = 0; mi < 2; mi++)
            #pragma unroll
            for (int nj = 0; nj < 7; nj++)
                fac[mi][nj] = (f32x4){0.f, 0.f, 0.f, 0.f};

        for (int k = 0; k < 7; k++) {
            if (k < 6) {
                unsigned short* wb = wsb[(k + 1) & 1];
                unsigned short* hb = hcb[(k + 1) & 1];
                *(u16x8*)&wb[sr * WS + sq * 8] = pr0;
                if (s2) *(u16x8*)&wb[(sr + 128) * WS + sq * 8] = pr1;
                if (k + 2 < 7) {
                    pr0 = *(const u16x8*)&W2z[sr * KP + (k + 2) * 32 + sq * 8];
                    if (s2) pr1 = *(const u16x8*)&W2z[(sr + 128) * KP + (k + 2) * 32 + sq * 8];
                } else if (it != 3) {
                    pr0 = *(const u16x8*)&W1z[sr * KP + sq * 8];
                    if (s2) pr1 = *(const u16x8*)&W1z[(sr + 128) * KP + sq * 8];
                }
                // hid chunk k+1 -> hc[(k+1)&1]
                #pragma unroll
                for (int t2 = 0; t2 < 2; t2++) {
                    const int c0 = (k + 1) * 32 + t2 * 16;
                    if (c0 >= wn && c0 < wn + 112) {
                        const int nj = (c0 - wn) >> 4;
                        #pragma unroll
                        for (int mi = 0; mi < 2; mi++)
                            #pragma unroll
                            for (int r = 0; r < 4; r++)
                                hb[(wm + mi * 16 + fq * 4 + r) * WS + t2 * 16 + fm] =
                                    hidp[mi][nj][r];
                    }
                }
            }
            const unsigned short* wr = wsb[k & 1];
            const unsigned short* hr = hcb[k & 1];
            bf16x8 af2[2], bf2[7];
            #pragma unroll
            for (int mi = 0; mi < 2; mi++)
                af2[mi] = *(const bf16x8*)&hr[(wm + mi * 16 + fm) * WS + fq * 8];
            #pragma unroll
            for (int nj = 0; nj < 7; nj++)
                bf2[nj] = *(const bf16x8*)&wr[(wn + nj * 16 + fm) * WS + fq * 8];
            #pragma unroll
            for (int mi = 0; mi < 2; mi++)
                #pragma unroll
                for (int nj = 0; nj < 7; nj++)
                    fac[mi][nj] = __builtin_amdgcn_mfma_f32_16x16x32_bf16(
                        af2[mi], bf2[nj], fac[mi][nj], 0, 0, 0);
            __syncthreads();
        }

        // h update (each wave owns rows wm..wm+32, cols wn..wn+112)
        #pragma unroll
        for (int mi = 0; mi < 2; mi++)
            #pragma unroll
            for (int nj = 0; nj < 7; nj++) {
                const int nn = wn + nj * 16 + fm;
                const float b2v = bfl[224 + nn];
                #pragma unroll
                for (int r = 0; r < 4; r++) {
                    const int row = wm + mi * 16 + fq * 4 + r;
                    const float fv = fac[mi][nj][r] + b2v;
                    hs[row * HS + nn] = f2bf(bf2f(hs[row * HS + nn]) + DT * fv);
                }
            }
        // next iteration's B0 barrier makes updates visible
    }

    __syncthreads();
    // write back h tile
    #pragma unroll
    for (int i = 0; i < 7; i++) {
        const int f = i * 512 + tid;
        const int r = f / 28, c = (f % 28) * 8;
        *(u16x8*)&hrow[(size_t)r * KP + c] = *(const u16x8*)&hs[r * HS + c];
    }
}

// ---------------------------------------------------------------------------
// Flash attention v5 (r13/r15/r16, passing): 512 threads, Q-tile 128, Q in
// LDS, no-max softmax (scores small; exp can't overflow fp32), of = pure
// MFMA accumulator.
// ---------------------------------------------------------------------------
__global__ __launch_bounds__(512) void flash_attn(
    const unsigned short* __restrict__ Qb, const unsigned short* __restrict__ Kb,
    const unsigned short* __restrict__ VT, unsigned short* __restrict__ ctx)
{
    constexpr int QS = 264;   // qs stride (u16)
    constexpr int KS = 264;   // ks stride
    constexpr int VS = 72;    // vs stride
    constexpr int PS = 72;    // ps stride
    extern __shared__ unsigned short lds[];
    unsigned short* qs = lds;                             // [128][264]
    unsigned short* ks = lds + 128 * QS;                  // [64][264]
    unsigned short* vs = lds + 128 * QS + 64 * KS;        // [256][72]
    unsigned short* ps = lds + 128 * QS + 64 * KS + 256 * VS;  // [8][16][72]

    const int tid = threadIdx.x;
    const int b = blockIdx.y, q0 = blockIdx.x * 128;
    const int lane = tid & 63, w = tid >> 6;
    const int fm = lane & 15, fq = lane >> 4;
    unsigned short* psw = ps + w * 16 * PS;

    const unsigned short* Qp = Qb + (size_t)b * Sc * Hc;
    const unsigned short* Kp = Kb + (size_t)b * Sc * Hc;
    const unsigned short* Vp = VT + (size_t)b * Hc * Sc;

    // stage Q tile once: 128 x 256
    #pragma unroll
    for (int i = 0; i < 8; i++) {
        const int v = i * 512 + tid;
        *(u16x8*)&qs[(v >> 5) * QS + (v & 31) * 8] =
            *(const u16x8*)&Qp[(size_t)(q0 + (v >> 5)) * Hc + (v & 31) * 8];
    }

    f32x4 of[16];
    #pragma unroll
    for (int nj = 0; nj < 16; nj++) of[nj] = (f32x4){0.f, 0.f, 0.f, 0.f};
    float lrun[4] = {0.f, 0.f, 0.f, 0.f};

    for (int c = 0; c < 16; c++) {
        __syncthreads();
        const int s0 = c * 64;
        #pragma unroll
        for (int i = 0; i < 4; i++) {
            const int v = i * 512 + tid;
            *(u16x8*)&ks[(v >> 5) * KS + (v & 31) * 8] =
                *(const u16x8*)&Kp[(size_t)(s0 + (v >> 5)) * Hc + (v & 31) * 8];
            *(u16x8*)&vs[(v >> 3) * VS + (v & 7) * 8] =
                *(const u16x8*)&Vp[(size_t)(v >> 3) * Sc + s0 + (v & 7) * 8];
        }
        __syncthreads();

        f32x4 sc[4];
        #pragma unroll
        for (int nj = 0; nj < 4; nj++) sc[nj] = (f32x4){0.f, 0.f, 0.f, 0.f};
        #pragma unroll
        for (int kc = 0; kc < 8; kc++) {
            const bf16x8 aq = *(const bf16x8*)&qs[(w * 16 + fm) * QS + kc * 32 + fq * 8];
            #pragma unroll
            for (int nj = 0; nj < 4; nj++) {
                const bf16x8 bk = *(const bf16x8*)&ks[(nj * 16 + fm) * KS + kc * 32 + fq * 8];
                sc[nj] = __builtin_amdgcn_mfma_f32_16x16x32_bf16(aq, bk, sc[nj], 0, 0, 0);
            }
        }

        float rsum[4] = {0.f, 0.f, 0.f, 0.f};
        #pragma unroll
        for (int nj = 0; nj < 4; nj++)
            #pragma unroll
            for (int r = 0; r < 4; r++) {
                const float p = __expf(sc[nj][r]);
                rsum[r] += p;
                psw[(fq * 4 + r) * PS + nj * 16 + fm] = f2bf(p);
            }
        #pragma unroll
        for (int r = 0; r < 4; r++) {
            float s = rsum[r];
            #pragma unroll
            for (int o = 8; o > 0; o >>= 1) s += __shfl_xor(s, o, 64);
            lrun[r] += s;
        }

        #pragma unroll
        for (int t = 0; t < 2; t++) {
            const bf16x8 ap = *(const bf16x8*)&psw[fm * PS + t * 32 + fq * 8];
            #pragma unroll
            for (int nj = 0; nj < 16; nj++) {
                const bf16x8 bv = *(const bf16x8*)&vs[(nj * 16 + fm) * VS + t * 32 + fq * 8];
                of[nj] = __builtin_amdgcn_mfma_f32_16x16x32_bf16(ap, bv, of[nj], 0, 0, 0);
            }
        }
    }

    float inv[4];
    #pragma unroll
    for (int r = 0; r < 4; r++) inv[r] = __frcp_rn(lrun[r]);
    #pragma unroll
    for (int nj = 0; nj < 16; nj++)
        #pragma unroll
        for (int r = 0; r < 4; r++)
            ctx[((size_t)b * Sc + q0 + w * 16 + fq * 4 + r) * Hc + nj * 16 + fm] =
                f2bf(of[nj][r] * inv[r]);
}

// ---------------------------------------------------------------------------
extern "C" void kernel_launch(void* const* d_in, const int* in_sizes, int n_in,
                              void* d_out, int out_size, void* d_ws, size_t ws_size,
                              hipStream_t stream)
{
    const float* eco_data = (const float*)d_in[0];
    const float* tran     = (const float*)d_in[1];
    const float* time_x   = (const float*)d_in[3];
    const float* W_eco    = (const float*)d_in[6];
    const float* b_eco    = (const float*)d_in[7];
    const float* W_in     = (const float*)d_in[8];
    const float* W_t      = (const float*)d_in[9];
    const float* b_in     = (const float*)d_in[10];
    const float* W_f1     = (const float*)d_in[11];
    const float* b_f1     = (const float*)d_in[12];
    const float* W_f2     = (const float*)d_in[13];
    const float* b_f2     = (const float*)d_in[14];
    const float* W_out    = (const float*)d_in[15];
    const float* b_out    = (const float*)d_in[16];
    const float* W_lin    = (const float*)d_in[17];
    const float* b_lin    = (const float*)d_in[18];
    float* out = (float*)d_out;

    // Workspace (offsets unchanged; P region unused)
    float* eco_vec = (float*)d_ws;
    unsigned short* hpad = (unsigned short*)(eco_vec + 8192);
    unsigned short* Qb = hpad + (size_t)3 * Mtot * KP;
    unsigned short* Kb = Qb + (size_t)Mtot * Hc;
    unsigned short* VT = Kb + (size_t)Mtot * Hc;
    unsigned short* P  = VT + (size_t)Mtot * Hc;   // unused
    unsigned short* WinT  = P + (size_t)Mtot * Sc;
    unsigned short* Wf1T  = WinT  + (size_t)3 * 256 * 256;
    unsigned short* Wf2T  = Wf1T  + (size_t)3 * 256 * KP;
    unsigned short* WoutT = Wf2T  + (size_t)3 * 256 * KP;
    unsigned short* WlinT = WoutT + (size_t)3 * 256 * KP;
    unsigned short* ctxb = hpad;                   // alias (h dead after qkv)

    // euler LDS: hs 59392 + 2x ws 17920 + 2x hc 10240 + bias 1792 = 117,504 B
    constexpr int EULER_LDS = 57856 * 2 + 448 * 4;
    static_assert(EULER_LDS == 117504, "euler lds");
    hipFuncSetAttribute((const void*)euler_fused,
                        hipFuncAttributeMaxDynamicSharedMemorySize, EULER_LDS);
    // flash v5 LDS: qs 67584 + ks 33792 + vs 36864 + ps 18432 = 156,672 B
    constexpr int FLASH_LDS = (128 * 264 + 64 * 264 + 256 * 72 + 8 * 16 * 72) * 2;
    static_assert(FLASH_LDS == 156672, "flash lds");
    hipFuncSetAttribute((const void*)flash_attn,
                        hipFuncAttributeMaxDynamicSharedMemorySize, FLASH_LDS);

    eco_kernel<<<Bc, Hc, 0, stream>>>(eco_data, W_eco, b_eco, eco_vec);

    const dim3 tb(16, 16);
    wtrans_kernel<<<dim3(16, 16, 3), tb, 0, stream>>>(W_in,  WinT,  256, 200, 256, 256);
    wtrans_kernel<<<dim3(16, 14, 3), tb, 0, stream>>>(W_f1,  Wf1T,  200, 200, 224, 256);
    wtrans_kernel<<<dim3(16, 14, 3), tb, 0, stream>>>(W_f2,  Wf2T,  200, 200, 224, 256);
    wtrans_kernel<<<dim3(16, 14, 3), tb, 0, stream>>>(W_out, WoutT, 200, 256, 224, 256);
    wtrans_kernel<<<dim3(8,  16, 1), tb, 0, stream>>>(W_lin, WlinT, 256,  96, 256, 128);

    const dim3 blk(256);

    // encode: hpad_k = tanh(tran @ W_in[k] + time_x*W_t[k] + b_in[k]), bf16 out
    mfma_gemm<MODE_ENC, float><<<dim3(2, 256, 3), blk, 0, stream>>>(
        tran, WinT, b_in, hpad, Mtot, KP, Hc, 256,
        0, 65536, Lc, (size_t)Mtot * KP, time_x, W_t, nullptr, nullptr, nullptr, nullptr);

    // fused 4-step Euler solve (r5 pipeline + biases in LDS)
    euler_fused<<<dim3(Mtot / 128, 3), 512, EULER_LDS, stream>>>(
        hpad, Wf1T, Wf2T, b_f1, b_f2);

    // qkv: Q*scale, K, V^T (V^T via LDS bounce) written bf16
    mfma_gemm<MODE_QKV, unsigned short><<<dim3(2, 256, 3), blk, 0, stream>>>(
        hpad, WoutT, b_out, Qb, Mtot, Hc, KP, KP,
        (size_t)Mtot * KP, 57344, Hc, 0, nullptr, nullptr, eco_vec, tran, Kb, VT);

    // fused attention (q-tile 128, 256 blocks)
    flash_attn<<<dim3(8, 32), 512, FLASH_LDS, stream>>>(Qb, Kb, VT, ctxb);

    // out = ctx @ W_lin + b_lin
    mfma_gemm<MODE_OUT, unsigned short><<<dim3(1, 256, 1), blk, 0, stream>>>(
        ctxb, WlinT, b_lin, out, Mtot, Pc, Hc, 256,
        0, 0, 0, 0, nullptr, nullptr, nullptr, nullptr, nullptr, nullptr);
}

// Round 18
// 520.921 us; speedup vs baseline: 1.0266x; 1.0266x over previous
//
#include <hip/hip_runtime.h>

// Problem constants (fixed by the reference)
constexpr int Bc = 32, Sc = 1024, Hc = 256, Pc = 96, Lc = 200, Oc = 200, Ec = 64;
constexpr int Mtot = Bc * Sc;
constexpr float DT = 0.25f;     // 1/N_EULER
constexpr int KP = 224;         // padded L/O dim (7*32)

enum { MODE_ENC = 0, MODE_QKV = 3, MODE_OUT = 4, MODE_BF16OUT = 5 };

typedef short bf16x8 __attribute__((ext_vector_type(8)));
typedef float f32x4 __attribute__((ext_vector_type(4)));
typedef unsigned short u16x8 __attribute__((ext_vector_type(8)));

__device__ inline unsigned short f2bf(float x) {
    union { float f; unsigned int u; } v; v.f = x;
    unsigned int r = v.u + 0x7FFFu + ((v.u >> 16) & 1u);   // RNE
    return (unsigned short)(r >> 16);
}
__device__ inline float bf2f(unsigned short x) {
    union { unsigned int u; float f; } v; v.u = ((unsigned int)x) << 16;
    return v.f;
}
__device__ inline float fast_tanh(float x) {
    float cx = fminf(fmaxf(x, -15.f), 15.f);
    float e = __expf(2.f * cx);
    return __fdividef(e - 1.f, e + 1.f);
}

// ---------------------------------------------------------------------------
__global__ __launch_bounds__(256) void eco_kernel(
    const float* __restrict__ eco_data, const float* __restrict__ W_eco,
    const float* __restrict__ b_eco, float* __restrict__ eco_vec)
{
    const int b = blockIdx.x, h = threadIdx.x;
    float acc = b_eco[h];
    #pragma unroll
    for (int e = 0; e < Ec; e++)
        acc = fmaf(eco_data[b * Ec + e], W_eco[(size_t)e * Hc + h], acc);
    eco_vec[(size_t)b * Hc + h] = acc;
}

// ---------------------------------------------------------------------------
// All five weight transposes in ONE dispatch (13 z-slices):
//   z 0-2 : W_in  [256][200] -> WinT  + z*256*256   (Kpad 256, Npad 256)
//   z 3-5 : W_f1  [200][200] -> Wf1T  + i*224*256   (Kpad 224, Npad 256)
//   z 6-8 : W_f2  [200][200] -> Wf2T  + i*224*256
//   z 9-11: W_out [200][256] -> WoutT + i*224*256
//   z 12  : W_lin [256][ 96] -> WlinT               (Kpad 256, Npad 128)
// ---------------------------------------------------------------------------
__global__ void wtrans_all(
    const float* __restrict__ W_in, const float* __restrict__ W_f1,
    const float* __restrict__ W_f2, const float* __restrict__ W_out,
    const float* __restrict__ W_lin,
    unsigned short* __restrict__ WinT, unsigned short* __restrict__ Wf1T,
    unsigned short* __restrict__ Wf2T, unsigned short* __restrict__ WoutT,
    unsigned short* __restrict__ WlinT)
{
    const int z = blockIdx.z;
    const int n = blockIdx.x * 16 + threadIdx.x;
    const int k = blockIdx.y * 16 + threadIdx.y;

    const float* W; unsigned short* WT;
    int K, N, Kpad, Npad;
    if (z < 3)       { W = W_in  + (size_t)z * 256 * 200;       WT = WinT  + (size_t)z * 256 * 256;       K = 256; N = 200; Kpad = 256; Npad = 256; }
    else if (z < 6)  { W = W_f1  + (size_t)(z - 3) * 200 * 200; WT = Wf1T  + (size_t)(z - 3) * 224 * 256; K = 200; N = 200; Kpad = 224; Npad = 256; }
    else if (z < 9)  { W = W_f2  + (size_t)(z - 6) * 200 * 200; WT = Wf2T  + (size_t)(z - 6) * 224 * 256; K = 200; N = 200; Kpad = 224; Npad = 256; }
    else if (z < 12) { W = W_out + (size_t)(z - 9) * 200 * 256; WT = WoutT + (size_t)(z - 9) * 224 * 256; K = 200; N = 256; Kpad = 224; Npad = 256; }
    else             { W = W_lin;                               WT = WlinT;                               K = 256; N =  96; Kpad = 256; Npad = 128; }

    if (n >= Npad || k >= Kpad) return;
    float v = (n < N && k < K) ? W[(size_t)k * N + n] : 0.f;
    WT[(size_t)n * Kpad + k] = f2bf(v);
}

// ---------------------------------------------------------------------------
// bf16 MFMA GEMM, 128x128 tile, 4 waves of 64x64, 16x16x32 MFMA.
// MODE_QKV z==2 writes V^T via an LDS bounce (two 64-row halves) instead of
// the 2KB-strided scalar u16 scatter (8x write amplification) — r14: -27 us.
// ---------------------------------------------------------------------------
template <int MODE, typename TA>
__global__ __launch_bounds__(256) void mfma_gemm(
    const TA* __restrict__ A, const unsigned short* __restrict__ WT,
    const float* __restrict__ bias, void* __restrict__ Cv,
    int M, int N, int K, int Kpad,
    size_t aStrideZ, size_t wStrideZ, size_t bStrideZ, size_t cStrideZ,
    const float* __restrict__ timev, const float* __restrict__ wtv,
    const float* __restrict__ eco, const float* __restrict__ trandat,
    unsigned short* __restrict__ Ck, unsigned short* __restrict__ Cvt)
{
    constexpr int LDS_S = 40;
    __shared__ unsigned short SM[128 * LDS_S * 2];   // As | Bs
    unsigned short* As = SM;
    unsigned short* Bs = SM + 128 * LDS_S;

    const int tid = threadIdx.x;
    const int z = blockIdx.z;
    const int m0 = blockIdx.y * 128;
    const int n0 = blockIdx.x * 128;

    A    += (size_t)z * aStrideZ;
    WT   += (size_t)z * wStrideZ;
    bias += (size_t)z * bStrideZ;
    float* Cf = (float*)Cv + (size_t)z * cStrideZ;
    unsigned short* Cu = (unsigned short*)Cv + (size_t)z * cStrideZ;
    const float* wtp = wtv ? (wtv + (size_t)z * Lc) : nullptr;

    const int lane = tid & 63, wave = tid >> 6;
    const int wm = (wave & 1) * 64, wn = (wave >> 1) * 64;
    const int fm = lane & 15, fq = lane >> 4;

    f32x4 acc[4][4];
    #pragma unroll
    for (int i = 0; i < 4; i++)
        #pragma unroll
        for (int j = 0; j < 4; j++)
            acc[i][j] = (f32x4){0.f, 0.f, 0.f, 0.f};

    for (int k0 = 0; k0 < K; k0 += 32) {
        if (k0) __syncthreads();
        #pragma unroll
        for (int i = 0; i < 4; i++) {
            const int f = i * 256 + tid;
            const int row = f >> 3, kq = f & 7;
            const int k = k0 + kq * 4;
            ushort4 s;
            if constexpr (sizeof(TA) == 4) {
                float4 v = {0.f, 0.f, 0.f, 0.f};
                if (k < K) v = *(const float4*)((const float*)A + (size_t)(m0 + row) * K + k);
                s.x = f2bf(v.x); s.y = f2bf(v.y); s.z = f2bf(v.z); s.w = f2bf(v.w);
            } else {
                s = make_ushort4(0, 0, 0, 0);
                if (k < K) s = *(const ushort4*)((const unsigned short*)A + (size_t)(m0 + row) * K + k);
            }
            *(ushort4*)&As[row * LDS_S + kq * 4] = s;
        }
        #pragma unroll
        for (int i = 0; i < 2; i++) {
            const int f = i * 256 + tid;
            const int row = f >> 2, q = f & 3;
            u16x8 v = *(const u16x8*)(WT + (size_t)(n0 + row) * Kpad + k0 + q * 8);
            *(u16x8*)&Bs[row * LDS_S + q * 8] = v;
        }
        __syncthreads();

        bf16x8 af[4], bfr[4];
        #pragma unroll
        for (int mi = 0; mi < 4; mi++)
            af[mi] = *(const bf16x8*)&As[(wm + mi * 16 + fm) * LDS_S + fq * 8];
        #pragma unroll
        for (int nj = 0; nj < 4; nj++)
            bfr[nj] = *(const bf16x8*)&Bs[(wn + nj * 16 + fm) * LDS_S + fq * 8];
        #pragma unroll
        for (int mi = 0; mi < 4; mi++)
            #pragma unroll
            for (int nj = 0; nj < 4; nj++)
                acc[mi][nj] = __builtin_amdgcn_mfma_f32_16x16x32_bf16(
                    af[mi], bfr[nj], acc[mi][nj], 0, 0, 0);
    }

    // ---- V^T epilogue (MODE_QKV, z==2): LDS bounce, coalesced writes ----
    if (MODE == MODE_QKV && z == 2) {
        constexpr int BSTR = 136;   // bounce row stride (u16)
        const int bq = m0 >> 10, sq0 = m0 & (Sc - 1);
        const int myhalf = wn >> 6;             // wave's n-half (0 or 1)
        #pragma unroll
        for (int half = 0; half < 2; half++) {
            __syncthreads();                    // SM free
            if (myhalf == half) {
                #pragma unroll
                for (int mi = 0; mi < 4; mi++)
                    #pragma unroll
                    for (int nj = 0; nj < 4; nj++) {
                        const int nn = n0 + wn + nj * 16 + fm;
                        const float bv = bias[nn];
                        const float ev = eco[(size_t)bq * Hc + nn];
                        #pragma unroll
                        for (int r = 0; r < 4; r++) {
                            const int mm = m0 + wm + mi * 16 + fq * 4 + r;
                            float v = acc[mi][nj][r] + bv + ev;
                            if (trandat[(size_t)mm * Hc + (Hc - 1)] == 0.f) v = 0.f;
                            SM[(nj * 16 + fm) * BSTR + wm + mi * 16 + fq * 4 + r] = f2bf(v);
                        }
                    }
            }
            __syncthreads();                    // bounce half ready
            #pragma unroll
            for (int i = 0; i < 4; i++) {
                const int vv = i * 256 + tid;   // 1024 = 64 rows x 16 vecs
                const int nl = vv >> 4, vc = vv & 15;
                *(u16x8*)&Cvt[((size_t)bq * Hc + n0 + half * 64 + nl) * Sc + sq0 + vc * 8] =
                    *(const u16x8*)&SM[nl * BSTR + vc * 8];
            }
        }
        return;
    }

    // ---- standard epilogue: C/D layout col = lane&15, row = quad*4 + reg ----
    #pragma unroll
    for (int mi = 0; mi < 4; mi++) {
        #pragma unroll
        for (int nj = 0; nj < 4; nj++) {
            const int nn = n0 + wn + nj * 16 + fm;
            if (nn >= N) continue;
            const float bv = (MODE == MODE_BF16OUT) ? 0.f
                           : ((MODE == MODE_ENC && nn >= Lc) ? 0.f : bias[nn]);
            #pragma unroll
            for (int r = 0; r < 4; r++) {
                const int mm = m0 + wm + mi * 16 + fq * 4 + r;
                float v = acc[mi][nj][r] + bv;
                if (MODE == MODE_ENC) {
                    float vv = (nn < Lc) ? fast_tanh(v + timev[mm] * wtp[nn]) : 0.f;
                    Cu[(size_t)mm * N + nn] = f2bf(vv);
                } else if (MODE == MODE_QKV) {
                    v += eco[(size_t)(mm >> 10) * Hc + nn];
                    if (trandat[(size_t)mm * Hc + (Hc - 1)] == 0.f) v = 0.f;
                    if (z == 0)      ((unsigned short*)Cv)[(size_t)mm * Hc + nn] = f2bf(v * 0.0625f);
                    else             Ck[(size_t)mm * Hc + nn] = f2bf(v);
                } else if (MODE == MODE_BF16OUT) {
                    Cu[(size_t)mm * N + nn] = f2bf(v);
                } else {
                    Cf[(size_t)mm * N + nn] = v;
                }
            }
        }
    }
}

// ---------------------------------------------------------------------------
// Fused 4-iteration Euler solve — r5/r16 version VERBATIM (best measured:
// 216.6/217.2 us, reproduced twice). 512 threads, 128 rows/block, wave tile
// 32x112, dbuf W + dbuf hid-chunk LDS, 1 barrier/chunk, hidp + bias caches
// in registers, h update = LDS RMW. Carries ~38 MB hidden scratch spill
// (WRITE 81 vs 43 ideal) — r17 proved removing bias regs makes it WORSE
// (226 us, spill grew); this exact register mix is the empirical optimum.
// Dynamic LDS 115,712 B.
// ---------------------------------------------------------------------------
__global__ __launch_bounds__(512, 2) void euler_fused(
    unsigned short* __restrict__ hg,       // [3][M][224] bf16, in/out
    const unsigned short* __restrict__ W1, // [3][256][224] bf16
    const unsigned short* __restrict__ W2, // [3][256][224] bf16
    const float* __restrict__ b1g, const float* __restrict__ b2g)
{
    constexpr int HS = 232;   // h LDS stride (u16)
    constexpr int WS = 40;    // W / hid chunk stride (u16)
    extern __shared__ unsigned short lds[];
    unsigned short* hs  = lds;                 // [128][232]  59,392 B
    unsigned short* wsb[2] = { lds + 29696, lds + 38656 };   // [224][40] each
    unsigned short* hcb[2] = { lds + 47616, lds + 52736 };   // [128][40] each

    const int tid = threadIdx.x;
    const int z = blockIdx.y;
    const int m0 = blockIdx.x * 128;
    unsigned short* hrow = hg + ((size_t)z * Mtot + m0) * KP;
    const unsigned short* W1z = W1 + (size_t)z * 256 * KP;
    const unsigned short* W2z = W2 + (size_t)z * 256 * KP;

    const int lane = tid & 63, w = tid >> 6;
    const int wm = (w & 3) * 32, wn = (w >> 2) * 112;
    const int fm = lane & 15, fq = lane >> 4;

    const int sr = tid >> 2, sq = tid & 3;
    const bool s2 = (tid < 384);

    // per-thread bias caches (register-resident — empirically fastest, r17)
    float b1r[7], b2r[7];
    #pragma unroll
    for (int nj = 0; nj < 7; nj++) {
        const int nn = wn + nj * 16 + fm;
        b1r[nj] = (nn < Oc) ? b1g[z * Oc + nn] : 0.f;
        b2r[nj] = (nn < Lc) ? b2g[z * Lc + nn] : 0.f;
    }

    // prefetch W1 chunk 0
    u16x8 pr0, pr1;
    pr0 = *(const u16x8*)&W1z[sr * KP + sq * 8];
    if (s2) pr1 = *(const u16x8*)&W1z[(sr + 128) * KP + sq * 8];

    // stage h tile: 128 x 224
    #pragma unroll
    for (int i = 0; i < 7; i++) {
        const int f = i * 512 + tid;
        const int r = f / 28, c = (f % 28) * 8;
        *(u16x8*)&hs[r * HS + c] = *(const u16x8*)&hrow[(size_t)r * KP + c];
    }

    for (int it = 0; it < 4; it++) {
        // ================= phase 1: hid = tanh(h @ W1 + b1) =================
        __syncthreads();                       // B0: hs/update visible, ws free
        *(u16x8*)&wsb[0][sr * WS + sq * 8] = pr0;
        if (s2) *(u16x8*)&wsb[0][(sr + 128) * WS + sq * 8] = pr1;
        pr0 = *(const u16x8*)&W1z[sr * KP + 32 + sq * 8];
        if (s2) pr1 = *(const u16x8*)&W1z[(sr + 128) * KP + 32 + sq * 8];
        __syncthreads();                       // B1: ws[0] ready

        f32x4 acc[2][7];
        #pragma unroll
        for (int mi = 0; mi < 2; mi++)
            #pragma unroll
            for (int nj = 0; nj < 7; nj++)
                acc[mi][nj] = (f32x4){0.f, 0.f, 0.f, 0.f};

        for (int k = 0; k < 7; k++) {
            if (k < 6) {
                unsigned short* wb = wsb[(k + 1) & 1];
                *(u16x8*)&wb[sr * WS + sq * 8] = pr0;
                if (s2) *(u16x8*)&wb[(sr + 128) * WS + sq * 8] = pr1;
                const unsigned short* src = (k + 2 < 7) ? (W1z + (k + 2) * 32) : W2z;
                pr0 = *(const u16x8*)&src[sr * KP + sq * 8];
                if (s2) pr1 = *(const u16x8*)&src[(sr + 128) * KP + sq * 8];
            }
            const unsigned short* wr = wsb[k & 1];
            bf16x8 af[2], bfr[7];
            #pragma unroll
            for (int mi = 0; mi < 2; mi++)
                af[mi] = *(const bf16x8*)&hs[(wm + mi * 16 + fm) * HS + k * 32 + fq * 8];
            #pragma unroll
            for (int nj = 0; nj < 7; nj++)
                bfr[nj] = *(const bf16x8*)&wr[(wn + nj * 16 + fm) * WS + fq * 8];
            #pragma unroll
            for (int mi = 0; mi < 2; mi++)
                #pragma unroll
                for (int nj = 0; nj < 7; nj++)
                    acc[mi][nj] = __builtin_amdgcn_mfma_f32_16x16x32_bf16(
                        af[mi], bfr[nj], acc[mi][nj], 0, 0, 0);
            __syncthreads();
        }

        // bias + tanh, pack (C layout: col = fm, row = fq*4+r)
        unsigned short hidp[2][7][4];
        #pragma unroll
        for (int mi = 0; mi < 2; mi++)
            #pragma unroll
            for (int nj = 0; nj < 7; nj++)
                #pragma unroll
                for (int r = 0; r < 4; r++)
                    hidp[mi][nj][r] = f2bf(fast_tanh(acc[mi][nj][r] + b1r[nj]));

        // ================= phase 2: h += DT * (hid @ W2 + b2) ===============
        {
            *(u16x8*)&wsb[0][sr * WS + sq * 8] = pr0;
            if (s2) *(u16x8*)&wsb[0][(sr + 128) * WS + sq * 8] = pr1;
            pr0 = *(const u16x8*)&W2z[sr * KP + 32 + sq * 8];
            if (s2) pr1 = *(const u16x8*)&W2z[(sr + 128) * KP + 32 + sq * 8];
            // hid chunk 0 -> hc[0]
            #pragma unroll
            for (int t2 = 0; t2 < 2; t2++) {
                const int c0 = t2 * 16;
                if (c0 >= wn && c0 < wn + 112) {
                    const int nj = (c0 - wn) >> 4;
                    #pragma unroll
                    for (int mi = 0; mi < 2; mi++)
                        #pragma unroll
                        for (int r = 0; r < 4; r++)
                            hcb[0][(wm + mi * 16 + fq * 4 + r) * WS + t2 * 16 + fm] =
                                hidp[mi][nj][r];
                }
            }
        }
        __syncthreads();                       // ws[0]/hc[0] ready

        f32x4 fac[2][7];
        #pragma unroll
        for (int mi = 0; mi < 2; mi++)
            #pragma unroll
            for (int nj = 0; nj < 7; nj++)
                fac[mi][nj] = (f32x4){0.f, 0.f, 0.f, 0.f};

        for (int k = 0; k < 7; k++) {
            if (k < 6) {
                unsigned short* wb = wsb[(k + 1) & 1];
                unsigned short* hb = hcb[(k + 1) & 1];
                *(u16x8*)&wb[sr * WS + sq * 8] = pr0;
                if (s2) *(u16x8*)&wb[(sr + 128) * WS + sq * 8] = pr1;
                if (k + 2 < 7) {
                    pr0 = *(const u16x8*)&W2z[sr * KP + (k + 2) * 32 + sq * 8];
                    if (s2) pr1 = *(const u16x8*)&W2z[(sr + 128) * KP + (k + 2) * 32 + sq * 8];
                } else if (it != 3) {
                    pr0 = *(const u16x8*)&W1z[sr * KP + sq * 8];
                    if (s2) pr1 = *(const u16x8*)&W1z[(sr + 128) * KP + sq * 8];
                }
                // hid chunk k+1 -> hc[(k+1)&1]
                #pragma unroll
                for (int t2 = 0; t2 < 2; t2++) {
                    const int c0 = (k + 1) * 32 + t2 * 16;
                    if (c0 >= wn && c0 < wn + 112) {
                        const int nj = (c0 - wn) >> 4;
                        #pragma unroll
                        for (int mi = 0; mi < 2; mi++)
                            #pragma unroll
                            for (int r = 0; r < 4; r++)
                                hb[(wm + mi * 16 + fq * 4 + r) * WS + t2 * 16 + fm] =
                                    hidp[mi][nj][r];
                    }
                }
            }
            const unsigned short* wr = wsb[k & 1];
            const unsigned short* hr = hcb[k & 1];
            bf16x8 af2[2], bf2[7];
            #pragma unroll
            for (int mi = 0; mi < 2; mi++)
                af2[mi] = *(const bf16x8*)&hr[(wm + mi * 16 + fm) * WS + fq * 8];
            #pragma unroll
            for (int nj = 0; nj < 7; nj++)
                bf2[nj] = *(const bf16x8*)&wr[(wn + nj * 16 + fm) * WS + fq * 8];
            #pragma unroll
            for (int mi = 0; mi < 2; mi++)
                #pragma unroll
                for (int nj = 0; nj < 7; nj++)
                    fac[mi][nj] = __builtin_amdgcn_mfma_f32_16x16x32_bf16(
                        af2[mi], bf2[nj], fac[mi][nj], 0, 0, 0);
            __syncthreads();
        }

        // h update (each wave owns rows wm..wm+32, cols wn..wn+112)
        #pragma unroll
        for (int mi = 0; mi < 2; mi++)
            #pragma unroll
            for (int nj = 0; nj < 7; nj++) {
                const int nn = wn + nj * 16 + fm;
                #pragma unroll
                for (int r = 0; r < 4; r++) {
                    const int row = wm + mi * 16 + fq * 4 + r;
                    const float fv = fac[mi][nj][r] + b2r[nj];
                    hs[row * HS + nn] = f2bf(bf2f(hs[row * HS + nn]) + DT * fv);
                }
            }
        // next iteration's B0 barrier makes updates visible
    }

    __syncthreads();
    // write back h tile
    #pragma unroll
    for (int i = 0; i < 7; i++) {
        const int f = i * 512 + tid;
        const int r = f / 28, c = (f % 28) * 8;
        *(u16x8*)&hrow[(size_t)r * KP + c] = *(const u16x8*)&hs[r * HS + c];
    }
}

// ---------------------------------------------------------------------------
// Flash attention v5 (r13/r15/r16, passing): 512 threads, Q-tile 128, Q in
// LDS, no-max softmax (scores small; exp can't overflow fp32), of = pure
// MFMA accumulator.
// ---------------------------------------------------------------------------
__global__ __launch_bounds__(512) void flash_attn(
    const unsigned short* __restrict__ Qb, const unsigned short* __restrict__ Kb,
    const unsigned short* __restrict__ VT, unsigned short* __restrict__ ctx)
{
    constexpr int QS = 264;   // qs stride (u16)
    constexpr int KS = 264;   // ks stride
    constexpr int VS = 72;    // vs stride
    constexpr int PS = 72;    // ps stride
    extern __shared__ unsigned short lds[];
    unsigned short* qs = lds;                             // [128][264]
    unsigned short* ks = lds + 128 * QS;                  // [64][264]
    unsigned short* vs = lds + 128 * QS + 64 * KS;        // [256][72]
    unsigned short* ps = lds + 128 * QS + 64 * KS + 256 * VS;  // [8][16][72]

    const int tid = threadIdx.x;
    const int b = blockIdx.y, q0 = blockIdx.x * 128;
    const int lane = tid & 63, w = tid >> 6;
    const int fm = lane & 15, fq = lane >> 4;
    unsigned short* psw = ps + w * 16 * PS;

    const unsigned short* Qp = Qb + (size_t)b * Sc * Hc;
    const unsigned short* Kp = Kb + (size_t)b * Sc * Hc;
    const unsigned short* Vp = VT + (size_t)b * Hc * Sc;

    // stage Q tile once: 128 x 256
    #pragma unroll
    for (int i = 0; i < 8; i++) {
        const int v = i * 512 + tid;
        *(u16x8*)&qs[(v >> 5) * QS + (v & 31) * 8] =
            *(const u16x8*)&Qp[(size_t)(q0 + (v >> 5)) * Hc + (v & 31) * 8];
    }

    f32x4 of[16];
    #pragma unroll
    for (int nj = 0; nj < 16; nj++) of[nj] = (f32x4){0.f, 0.f, 0.f, 0.f};
    float lrun[4] = {0.f, 0.f, 0.f, 0.f};

    for (int c = 0; c < 16; c++) {
        __syncthreads();
        const int s0 = c * 64;
        #pragma unroll
        for (int i = 0; i < 4; i++) {
            const int v = i * 512 + tid;
            *(u16x8*)&ks[(v >> 5) * KS + (v & 31) * 8] =
                *(const u16x8*)&Kp[(size_t)(s0 + (v >> 5)) * Hc + (v & 31) * 8];
            *(u16x8*)&vs[(v >> 3) * VS + (v & 7) * 8] =
                *(const u16x8*)&Vp[(size_t)(v >> 3) * Sc + s0 + (v & 7) * 8];
        }
        __syncthreads();

        f32x4 sc[4];
        #pragma unroll
        for (int nj = 0; nj < 4; nj++) sc[nj] = (f32x4){0.f, 0.f, 0.f, 0.f};
        #pragma unroll
        for (int kc = 0; kc < 8; kc++) {
            const bf16x8 aq = *(const bf16x8*)&qs[(w * 16 + fm) * QS + kc * 32 + fq * 8];
            #pragma unroll
            for (int nj = 0; nj < 4; nj++) {
                const bf16x8 bk = *(const bf16x8*)&ks[(nj * 16 + fm) * KS + kc * 32 + fq * 8];
                sc[nj] = __builtin_amdgcn_mfma_f32_16x16x32_bf16(aq, bk, sc[nj], 0, 0, 0);
            }
        }

        float rsum[4] = {0.f, 0.f, 0.f, 0.f};
        #pragma unroll
        for (int nj = 0; nj < 4; nj++)
            #pragma unroll
            for (int r = 0; r < 4; r++) {
                const float p = __expf(sc[nj][r]);
                rsum[r] += p;
                psw[(fq * 4 + r) * PS + nj * 16 + fm] = f2bf(p);
            }
        #pragma unroll
        for (int r = 0; r < 4; r++) {
            float s = rsum[r];
            #pragma unroll
            for (int o = 8; o > 0; o >>= 1) s += __shfl_xor(s, o, 64);
            lrun[r] += s;
        }

        #pragma unroll
        for (int t = 0; t < 2; t++) {
            const bf16x8 ap = *(const bf16x8*)&psw[fm * PS + t * 32 + fq * 8];
            #pragma unroll
            for (int nj = 0; nj < 16; nj++) {
                const bf16x8 bv = *(const bf16x8*)&vs[(nj * 16 + fm) * VS + t * 32 + fq * 8];
                of[nj] = __builtin_amdgcn_mfma_f32_16x16x32_bf16(ap, bv, of[nj], 0, 0, 0);
            }
        }
    }

    float inv[4];
    #pragma unroll
    for (int r = 0; r < 4; r++) inv[r] = __frcp_rn(lrun[r]);
    #pragma unroll
    for (int nj = 0; nj < 16; nj++)
        #pragma unroll
        for (int r = 0; r < 4; r++)
            ctx[((size_t)b * Sc + q0 + w * 16 + fq * 4 + r) * Hc + nj * 16 + fm] =
                f2bf(of[nj][r] * inv[r]);
}

// ---------------------------------------------------------------------------
extern "C" void kernel_launch(void* const* d_in, const int* in_sizes, int n_in,
                              void* d_out, int out_size, void* d_ws, size_t ws_size,
                              hipStream_t stream)
{
    const float* eco_data = (const float*)d_in[0];
    const float* tran     = (const float*)d_in[1];
    const float* time_x   = (const float*)d_in[3];
    const float* W_eco    = (const float*)d_in[6];
    const float* b_eco    = (const float*)d_in[7];
    const float* W_in     = (const float*)d_in[8];
    const float* W_t      = (const float*)d_in[9];
    const float* b_in     = (const float*)d_in[10];
    const float* W_f1     = (const float*)d_in[11];
    const float* b_f1     = (const float*)d_in[12];
    const float* W_f2     = (const float*)d_in[13];
    const float* b_f2     = (const float*)d_in[14];
    const float* W_out    = (const float*)d_in[15];
    const float* b_out    = (const float*)d_in[16];
    const float* W_lin    = (const float*)d_in[17];
    const float* b_lin    = (const float*)d_in[18];
    float* out = (float*)d_out;

    // Workspace (offsets unchanged; P region unused)
    float* eco_vec = (float*)d_ws;
    unsigned short* hpad = (unsigned short*)(eco_vec + 8192);
    unsigned short* Qb = hpad + (size_t)3 * Mtot * KP;
    unsigned short* Kb = Qb + (size_t)Mtot * Hc;
    unsigned short* VT = Kb + (size_t)Mtot * Hc;
    unsigned short* P  = VT + (size_t)Mtot * Hc;   // unused
    unsigned short* WinT  = P + (size_t)Mtot * Sc;
    unsigned short* Wf1T  = WinT  + (size_t)3 * 256 * 256;
    unsigned short* Wf2T  = Wf1T  + (size_t)3 * 256 * KP;
    unsigned short* WoutT = Wf2T  + (size_t)3 * 256 * KP;
    unsigned short* WlinT = WoutT + (size_t)3 * 256 * KP;
    unsigned short* ctxb = hpad;                   // alias (h dead after qkv)

    // euler (r5/r16) LDS: hs 59392 + 2x ws 17920 + 2x hc 10240 = 115,712 B
    constexpr int EULER_LDS = 57856 * 2;
    static_assert(EULER_LDS == 115712, "euler lds");
    hipFuncSetAttribute((const void*)euler_fused,
                        hipFuncAttributeMaxDynamicSharedMemorySize, EULER_LDS);
    // flash v5 LDS: qs 67584 + ks 33792 + vs 36864 + ps 18432 = 156,672 B
    constexpr int FLASH_LDS = (128 * 264 + 64 * 264 + 256 * 72 + 8 * 16 * 72) * 2;
    static_assert(FLASH_LDS == 156672, "flash lds");
    hipFuncSetAttribute((const void*)flash_attn,
                        hipFuncAttributeMaxDynamicSharedMemorySize, FLASH_LDS);

    eco_kernel<<<Bc, Hc, 0, stream>>>(eco_data, W_eco, b_eco, eco_vec);

    // all 5 weight transposes in one dispatch (13 z-slices)
    wtrans_all<<<dim3(16, 16, 13), dim3(16, 16), 0, stream>>>(
        W_in, W_f1, W_f2, W_out, W_lin, WinT, Wf1T, Wf2T, WoutT, WlinT);

    const dim3 blk(256);

    // encode: hpad_k = tanh(tran @ W_in[k] + time_x*W_t[k] + b_in[k]), bf16 out
    mfma_gemm<MODE_ENC, float><<<dim3(2, 256, 3), blk, 0, stream>>>(
        tran, WinT, b_in, hpad, Mtot, KP, Hc, 256,
        0, 65536, Lc, (size_t)Mtot * KP, time_x, W_t, nullptr, nullptr, nullptr, nullptr);

    // fused 4-step Euler solve (r5/r16 config: 128 rows/block, dbuf + prefetch)
    euler_fused<<<dim3(Mtot / 128, 3), 512, EULER_LDS, stream>>>(
        hpad, Wf1T, Wf2T, b_f1, b_f2);

    // qkv: Q*scale, K, V^T (V^T via LDS bounce) written bf16
    mfma_gemm<MODE_QKV, unsigned short><<<dim3(2, 256, 3), blk, 0, stream>>>(
        hpad, WoutT, b_out, Qb, Mtot, Hc, KP, KP,
        (size_t)Mtot * KP, 57344, Hc, 0, nullptr, nullptr, eco_vec, tran, Kb, VT);

    // fused attention (q-tile 128, 256 blocks)
    flash_attn<<<dim3(8, 32), 512, FLASH_LDS, stream>>>(Qb, Kb, VT, ctxb);

    // out = ctx @ W_lin + b_lin
    mfma_gemm<MODE_OUT, unsigned short><<<dim3(1, 256, 1), blk, 0, stream>>>(
        ctxb, WlinT, b_lin, out, Mtot, Pc, Hc, 256,
        0, 0, 0, 0, nullptr, nullptr, nullptr, nullptr, nullptr, nullptr);
}